// Round 1
// baseline (1903.384 us; speedup 1.0000x reference)
//
#include <hip/hip_runtime.h>
#include <hip/hip_bf16.h>
#include <stdint.h>

#define VOCAB 30000
#define EMBED 256
#define HID   128
#define BB    256
#define TT    512
#define G4    (4*HID)    // 512 gate columns per direction
#define GW    (2*G4)     // 1024 columns in embW (fw | bw)

typedef _Float16 h2f __attribute__((ext_vector_type(2)));

__device__ __forceinline__ float sigm(float x){ return 1.0f/(1.0f + __expf(-x)); }

__device__ __forceinline__ float dot2f(uint32_t hw, h2f u, float acc){
  union { uint32_t u32; h2f v; } cv; cv.u32 = hw;
#if __has_builtin(__builtin_amdgcn_fdot2)
  return __builtin_amdgcn_fdot2(cv.v, u, acc, false);
#else
  return acc + (float)cv.v[0]*(float)u[0] + (float)cv.v[1]*(float)u[1];
#endif
}

// ---------------------------------------------------------------------------
// Kernel 1: embW[v][g] = emb[v][:] @ [W_fw | W_bw][:, g] + [b_fw | b_bw][g]
// Block: 64 vocab rows x 1024 cols, 1024 threads, each thread 16 rows x 4 cols.
// ---------------------------------------------------------------------------
__global__ __launch_bounds__(1024, 4) void embw_k(
    const float* __restrict__ emb,
    const float* __restrict__ Wf, const float* __restrict__ Wb,
    const float* __restrict__ bf, const float* __restrict__ bb,
    float* __restrict__ EW)
{
  __shared__ float et[64*EMBED];        // 64 KB tile of emb
  const int tid = threadIdx.x;
  const int v0  = blockIdx.x * 64;
  const int nr  = min(64, VOCAB - v0);

  // coalesced float4 tile load
  const float4* src = (const float4*)(emb + (size_t)v0*EMBED);
  float4* d4 = (float4*)et;
  const int n4 = nr * (EMBED/4);
  for (int i = tid; i < n4; i += 1024) d4[i] = src[i];
  __syncthreads();

  const int cg = (tid & 255) * 4;       // column group 0..1020
  const int rg = (tid >> 8) * 16;       // row group 0,16,32,48
  const float* Ws = (cg < G4) ? (Wf + cg) : (Wb + (cg - G4));

  float ax[16]={0.f},ay[16]={0.f},az[16]={0.f},aw[16]={0.f};

  for (int k = 0; k < EMBED; k += 4){
    const float4 w0 = *(const float4*)(Ws + (size_t)(k  )*G4);
    const float4 w1 = *(const float4*)(Ws + (size_t)(k+1)*G4);
    const float4 w2 = *(const float4*)(Ws + (size_t)(k+2)*G4);
    const float4 w3 = *(const float4*)(Ws + (size_t)(k+3)*G4);
    #pragma unroll
    for (int r = 0; r < 16; ++r){
      const float4 e4 = *(const float4*)(&et[(rg+r)*EMBED + k]);
      #define FMA4(E, W) ax[r]=fmaf(E,W.x,ax[r]); ay[r]=fmaf(E,W.y,ay[r]); \
                         az[r]=fmaf(E,W.z,az[r]); aw[r]=fmaf(E,W.w,aw[r]);
      FMA4(e4.x, w0) FMA4(e4.y, w1) FMA4(e4.z, w2) FMA4(e4.w, w3)
      #undef FMA4
    }
  }

  const float* bsrc = (cg < G4) ? (bf + cg) : (bb + (cg - G4));
  const float4 bias = *(const float4*)bsrc;
  #pragma unroll
  for (int r = 0; r < 16; ++r){
    const int row = rg + r;
    if (row < nr){
      float4 o;
      o.x = ax[r] + bias.x; o.y = ay[r] + bias.y;
      o.z = az[r] + bias.z; o.w = aw[r] + bias.w;
      *(float4*)(EW + (size_t)(v0+row)*GW + cg) = o;
    }
  }
}

// ---------------------------------------------------------------------------
// Kernel 2: recurrent scan. One block per (batch, direction) sequence.
// 512 threads: thread c owns gate-column c. U[:, c] lives in 64 f16x2 VGPRs.
// h (128 f16) broadcast per step: ds_read one dword/lane -> v_readlane -> SGPR
// -> v_dot2_f32_f16 against register U. Gates computed by threads 0..127.
// ---------------------------------------------------------------------------
__global__ __launch_bounds__(512, 4) void lstm_k(
    const int*   __restrict__ tokens,
    const float* __restrict__ EW,
    const float* __restrict__ Ufw, const float* __restrict__ Ubw,
    float* __restrict__ out)
{
  __shared__ int      tok[TT];          // 2 KB
  __shared__ float    zbuf[G4];         // 2 KB
  __shared__ uint32_t h2buf[HID/2];     // 256 B : packed f16 h

  const int tid  = threadIdx.x;
  const int lane = tid & 63;
  const int bid  = blockIdx.x;
  const int dir  = bid & 1;
  const int b    = bid >> 1;

  tok[tid] = tokens[b*TT + tid];
  if (tid < HID/2) h2buf[tid] = 0u;
  __syncthreads();

  // load U column c=tid into registers as f16 pairs (k, k+1)
  const float* U  = dir ? Ubw : Ufw;
  const float* Uc = U + tid;
  h2f u[64];
  #pragma unroll
  for (int i = 0; i < 64; ++i){
    const float uaf = Uc[(size_t)(2*i  )*G4];
    const float ubf = Uc[(size_t)(2*i+1)*G4];
    h2f tpack; tpack[0] = (_Float16)uaf; tpack[1] = (_Float16)ubf;
    u[i] = tpack;
  }

  const float* ewbase = EW + (size_t)dir*G4;
  const int t0 = dir ? (TT-1) : 0;
  float xw_cur = ewbase[(size_t)tok[t0]*GW + tid];

  float c_reg = 0.f, h_last = 0.f;
  float* outp = out + (size_t)b*TT*(2*HID) + (size_t)dir*HID + tid; // tid<HID only

  for (int s = 0; s < TT; ++s){
    const int t = dir ? (TT-1-s) : s;

    // prefetch next step's xw row (hidden under the dot loop)
    float xw_next = 0.f;
    if (s + 1 < TT){
      const int tn = dir ? (TT-2-s) : (s+1);
      xw_next = ewbase[(size_t)tok[tn]*GW + tid];
    }

    // z[c] = xw[c] + h . U[:,c]
    const uint32_t hv = h2buf[lane];
    float a0=0.f,a1=0.f,a2=0.f,a3=0.f,a4=0.f,a5=0.f,a6=0.f,a7=0.f;
    #pragma unroll
    for (int i = 0; i < 64; i += 8){
      a0 = dot2f((uint32_t)__builtin_amdgcn_readlane((int)hv, i+0), u[i+0], a0);
      a1 = dot2f((uint32_t)__builtin_amdgcn_readlane((int)hv, i+1), u[i+1], a1);
      a2 = dot2f((uint32_t)__builtin_amdgcn_readlane((int)hv, i+2), u[i+2], a2);
      a3 = dot2f((uint32_t)__builtin_amdgcn_readlane((int)hv, i+3), u[i+3], a3);
      a4 = dot2f((uint32_t)__builtin_amdgcn_readlane((int)hv, i+4), u[i+4], a4);
      a5 = dot2f((uint32_t)__builtin_amdgcn_readlane((int)hv, i+5), u[i+5], a5);
      a6 = dot2f((uint32_t)__builtin_amdgcn_readlane((int)hv, i+6), u[i+6], a6);
      a7 = dot2f((uint32_t)__builtin_amdgcn_readlane((int)hv, i+7), u[i+7], a7);
    }
    const float z = xw_cur + (((a0+a1)+(a2+a3)) + ((a4+a5)+(a6+a7)));
    zbuf[tid] = z;
    __syncthreads();

    if (tid < HID){
      const float zi = zbuf[tid];
      const float zf = zbuf[tid +   HID];
      const float zg = zbuf[tid + 2*HID];
      const float zo = zbuf[tid + 3*HID];
      const float cnew = sigm(zf)*c_reg + sigm(zi)*tanhf(zg);
      c_reg = cnew;
      const float hh = sigm(zo)*tanhf(cnew);
      h_last = hh;
      outp[(size_t)t*(2*HID)] = hh;                 // out[b][t][dir*H + j]
      ((_Float16*)h2buf)[tid] = (_Float16)hh;       // packed f16 h for next step
    }
    __syncthreads();
    xw_cur = xw_next;
  }

  if (tid < HID){
    const size_t O1 = (size_t)BB*TT*(2*HID);        // 33,554,432
    const size_t idx = (size_t)b*HID + tid;
    if (dir == 0){
      out[O1             + idx] = h_last;           // hf
      out[O1 +   (size_t)BB*HID + idx] = c_reg;     // cf
    } else {
      out[O1 + 2*(size_t)BB*HID + idx] = h_last;    // hb
      out[O1 + 3*(size_t)BB*HID + idx] = c_reg;     // cb
    }
  }
}

extern "C" void kernel_launch(void* const* d_in, const int* in_sizes, int n_in,
                              void* d_out, int out_size, void* d_ws, size_t ws_size,
                              hipStream_t stream)
{
  const int*   tokens = (const int*)  d_in[0];
  const float* emb    = (const float*)d_in[1];
  const float* Wf     = (const float*)d_in[2];
  const float* Ufw    = (const float*)d_in[3];
  const float* bf     = (const float*)d_in[4];
  const float* Wb     = (const float*)d_in[5];
  const float* Ubw    = (const float*)d_in[6];
  const float* bb     = (const float*)d_in[7];
  float* out = (float*)d_out;
  float* EW  = (float*)d_ws;          // 30000 x 1024 f32 = 122.88 MB

  embw_k<<<(VOCAB + 63)/64, 1024, 0, stream>>>(emb, Wf, Wb, bf, bb, EW);
  lstm_k<<<BB*2, 512, 0, stream>>>(tokens, EW, Ufw, Ubw, out);
}

// Round 2
// 887.102 us; speedup vs baseline: 2.1456x; 2.1456x over previous
//
#include <hip/hip_runtime.h>
#include <hip/hip_bf16.h>
#include <stdint.h>

#define VOCAB 30000
#define EMBED 256
#define HID   128
#define BB    256
#define TT    512
#define G4    (4*HID)    // 512 gate columns per direction
#define GW    (2*G4)     // 1024 columns in embW (fw | bw)

typedef _Float16 h2f   __attribute__((ext_vector_type(2)));
typedef _Float16 f16x8 __attribute__((ext_vector_type(8)));
typedef float    f32x4 __attribute__((ext_vector_type(4)));

__device__ __forceinline__ float sigm(float x){ return 1.0f/(1.0f + __expf(-x)); }

__device__ __forceinline__ float dot2f(uint32_t hw, h2f u, float acc){
  union { uint32_t u32; h2f v; } cv; cv.u32 = hw;
#if __has_builtin(__builtin_amdgcn_fdot2)
  return __builtin_amdgcn_fdot2(cv.v, u, acc, false);
#else
  return acc + (float)cv.v[0]*(float)u[0] + (float)cv.v[1]*(float)u[1];
#endif
}

// ---------------------------------------------------------------------------
// Kernel 1: EW[v][g] = emb[v][:] @ [Wf|Wb][:,g] + bias[g]   via MFMA f16.
// Block: 256 threads = 4 waves. Tile 64 rows x 64 cols; wave w owns 16 cols.
// A tile (64x256) staged f32->f16 in LDS with XOR-chunk swizzle; B fragments
// read straight from global (W is L2-resident) and cvt'd to f16 in-register.
// ---------------------------------------------------------------------------
__global__ __launch_bounds__(256, 4) void embw_mfma(
    const float* __restrict__ emb,
    const float* __restrict__ Wf, const float* __restrict__ Wb,
    const float* __restrict__ bf, const float* __restrict__ bb,
    float* __restrict__ EW)
{
  // swizzled index: f16_idx = row*256 + (k ^ ((row&7)<<3))  (XOR on k bits 3..5)
  __shared__ _Float16 As[64*EMBED];   // 32 KB
  const int tid = threadIdx.x;
  const int l   = tid & 63;
  const int w   = tid >> 6;
  const int r0  = blockIdx.x * 64;
  const int c0  = blockIdx.y * 64;
  const int nr  = min(64, VOCAB - r0);

  // ---- stage A tile: coalesced float4 loads, f16 convert, swizzled store ----
  const float4* asrc = (const float4*)(emb + (size_t)r0*EMBED);
  for (int i = tid; i < nr*(EMBED/4); i += 256){
    float4 v = asrc[i];
    const int row = i >> 6;            // 64 float4 per row
    const int kc  = (i & 63) * 4;
    const int ks  = kc ^ ((row & 7) << 3);
    _Float16* dst = &As[row*EMBED + ks];
    dst[0]=(_Float16)v.x; dst[1]=(_Float16)v.y;
    dst[2]=(_Float16)v.z; dst[3]=(_Float16)v.w;
  }
  __syncthreads();

  const int cl = w*16 + (l & 15);      // local col 0..63
  const int cg = c0 + cl;              // global col 0..1023
  const float* Wsrc = (cg < G4) ? (Wf + cg) : (Wb + (cg - G4));
  const int kg = (l >> 4) * 8;         // this lane's k-offset inside each K=32 step

  f32x4 acc[4] = {{0,0,0,0},{0,0,0,0},{0,0,0,0},{0,0,0,0}};

  for (int kk = 0; kk < EMBED/32; ++kk){
    const int kb = kk*32 + kg;
    // B fragment: B[k][col], lane holds col=l&15(+w*16), k = kb..kb+7
    f16x8 bfrag;
    #pragma unroll
    for (int j = 0; j < 8; ++j)
      bfrag[j] = (_Float16)Wsrc[(size_t)(kb + j)*G4];
    // A fragments: lane holds row = m*16 + (l&15), k = kb..kb+7 (swizzled)
    #pragma unroll
    for (int m = 0; m < 4; ++m){
      const int row = m*16 + (l & 15);
      const int ks  = kb ^ ((row & 7) << 3);
      f16x8 afrag = *(const f16x8*)&As[row*EMBED + ks];
      acc[m] = __builtin_amdgcn_mfma_f32_16x16x32_f16(afrag, bfrag, acc[m], 0, 0, 0);
    }
  }

  // ---- epilogue: bias + store. C layout: col=lane&15, row=(lane>>4)*4+reg ----
  const float bv = (cg < G4) ? bf[cg] : bb[cg - G4];
  #pragma unroll
  for (int m = 0; m < 4; ++m){
    #pragma unroll
    for (int r = 0; r < 4; ++r){
      const int vrow = r0 + m*16 + (l >> 4)*4 + r;
      if (vrow < VOCAB)
        EW[(size_t)vrow*GW + cg] = acc[m][r] + bv;
    }
  }
}

// ---------------------------------------------------------------------------
// Kernel 2: recurrent scan. One block per (batch, direction) sequence.
// 512 threads: thread c owns gate-column c. U[:, c] lives in 64 f16x2 VGPRs.
// h (128 f16) broadcast per step: LDS dword/lane -> v_readlane -> SGPR
// -> v_dot2_f32_f16 against register U. Gates computed by threads 0..127.
// ---------------------------------------------------------------------------
__global__ __launch_bounds__(512, 4) void lstm_k(
    const int*   __restrict__ tokens,
    const float* __restrict__ EW,
    const float* __restrict__ Ufw, const float* __restrict__ Ubw,
    float* __restrict__ out)
{
  __shared__ int      tok[TT];          // 2 KB
  __shared__ float    zbuf[G4];         // 2 KB
  __shared__ uint32_t h2buf[HID/2];     // 256 B : packed f16 h

  const int tid  = threadIdx.x;
  const int lane = tid & 63;
  const int bid  = blockIdx.x;
  const int dir  = bid & 1;
  const int b    = bid >> 1;

  tok[tid] = tokens[b*TT + tid];
  if (tid < HID/2) h2buf[tid] = 0u;
  __syncthreads();

  // load U column c=tid into registers as f16 pairs (k, k+1)
  const float* U  = dir ? Ubw : Ufw;
  const float* Uc = U + tid;
  h2f u[64];
  #pragma unroll
  for (int i = 0; i < 64; ++i){
    const float uaf = Uc[(size_t)(2*i  )*G4];
    const float ubf = Uc[(size_t)(2*i+1)*G4];
    h2f tpack; tpack[0] = (_Float16)uaf; tpack[1] = (_Float16)ubf;
    u[i] = tpack;
  }

  const float* ewbase = EW + (size_t)dir*G4;
  const int t0 = dir ? (TT-1) : 0;
  float xw_cur = ewbase[(size_t)tok[t0]*GW + tid];

  float c_reg = 0.f, h_last = 0.f;
  float* outp = out + (size_t)b*TT*(2*HID) + (size_t)dir*HID + tid; // tid<HID only

  for (int s = 0; s < TT; ++s){
    const int t = dir ? (TT-1-s) : s;

    // prefetch next step's xw row (hidden under the dot loop)
    float xw_next = 0.f;
    if (s + 1 < TT){
      const int tn = dir ? (TT-2-s) : (s+1);
      xw_next = ewbase[(size_t)tok[tn]*GW + tid];
    }

    // z[c] = xw[c] + h . U[:,c]
    const uint32_t hv = h2buf[lane];
    float a0=0.f,a1=0.f,a2=0.f,a3=0.f,a4=0.f,a5=0.f,a6=0.f,a7=0.f;
    #pragma unroll
    for (int i = 0; i < 64; i += 8){
      a0 = dot2f((uint32_t)__builtin_amdgcn_readlane((int)hv, i+0), u[i+0], a0);
      a1 = dot2f((uint32_t)__builtin_amdgcn_readlane((int)hv, i+1), u[i+1], a1);
      a2 = dot2f((uint32_t)__builtin_amdgcn_readlane((int)hv, i+2), u[i+2], a2);
      a3 = dot2f((uint32_t)__builtin_amdgcn_readlane((int)hv, i+3), u[i+3], a3);
      a4 = dot2f((uint32_t)__builtin_amdgcn_readlane((int)hv, i+4), u[i+4], a4);
      a5 = dot2f((uint32_t)__builtin_amdgcn_readlane((int)hv, i+5), u[i+5], a5);
      a6 = dot2f((uint32_t)__builtin_amdgcn_readlane((int)hv, i+6), u[i+6], a6);
      a7 = dot2f((uint32_t)__builtin_amdgcn_readlane((int)hv, i+7), u[i+7], a7);
    }
    const float z = xw_cur + (((a0+a1)+(a2+a3)) + ((a4+a5)+(a6+a7)));
    zbuf[tid] = z;
    __syncthreads();

    if (tid < HID){
      const float zi = zbuf[tid];
      const float zf = zbuf[tid +   HID];
      const float zg = zbuf[tid + 2*HID];
      const float zo = zbuf[tid + 3*HID];
      const float cnew = sigm(zf)*c_reg + sigm(zi)*tanhf(zg);
      c_reg = cnew;
      const float hh = sigm(zo)*tanhf(cnew);
      h_last = hh;
      outp[(size_t)t*(2*HID)] = hh;                 // out[b][t][dir*H + j]
      ((_Float16*)h2buf)[tid] = (_Float16)hh;       // packed f16 h for next step
    }
    __syncthreads();
    xw_cur = xw_next;
  }

  if (tid < HID){
    const size_t O1 = (size_t)BB*TT*(2*HID);        // 33,554,432
    const size_t idx = (size_t)b*HID + tid;
    if (dir == 0){
      out[O1             + idx] = h_last;           // hf
      out[O1 +   (size_t)BB*HID + idx] = c_reg;     // cf
    } else {
      out[O1 + 2*(size_t)BB*HID + idx] = h_last;    // hb
      out[O1 + 3*(size_t)BB*HID + idx] = c_reg;     // cb
    }
  }
}

extern "C" void kernel_launch(void* const* d_in, const int* in_sizes, int n_in,
                              void* d_out, int out_size, void* d_ws, size_t ws_size,
                              hipStream_t stream)
{
  const int*   tokens = (const int*)  d_in[0];
  const float* emb    = (const float*)d_in[1];
  const float* Wf     = (const float*)d_in[2];
  const float* Ufw    = (const float*)d_in[3];
  const float* bf     = (const float*)d_in[4];
  const float* Wb     = (const float*)d_in[5];
  const float* Ubw    = (const float*)d_in[6];
  const float* bb     = (const float*)d_in[7];
  float* out = (float*)d_out;
  float* EW  = (float*)d_ws;          // 30000 x 1024 f32 = 122.88 MB

  embw_mfma<<<dim3((VOCAB + 63)/64, GW/64), 256, 0, stream>>>(emb, Wf, Wb, bf, bb, EW);
  lstm_k<<<BB*2, 512, 0, stream>>>(tokens, EW, Ufw, Ubw, out);
}

// Round 3
// 716.853 us; speedup vs baseline: 2.6552x; 1.2375x over previous
//
#include <hip/hip_runtime.h>
#include <hip/hip_bf16.h>
#include <stdint.h>

#define VOCAB 30000
#define EMBED 256
#define HID   128
#define BB    256
#define TT    512
#define G4    (4*HID)    // 512 gate columns per direction
#define GW    (2*G4)     // 1024 columns in embW (fw | bw)
#define BPB   4          // batches per lstm block

typedef _Float16 f16x8 __attribute__((ext_vector_type(8)));
typedef float    f32x4 __attribute__((ext_vector_type(4)));

__device__ __forceinline__ float sigm(float x){
  return 1.0f / (1.0f + __expf(-x));
}
__device__ __forceinline__ float fast_tanh(float x){
  // (e^2x - 1)/(e^2x + 1); saturates correctly for |x| large
  float e = __expf(2.0f * x);
  return 1.0f - 2.0f / (e + 1.0f);
}

// ---------------------------------------------------------------------------
// Kernel 1: EW[v][g] = emb[v][:] @ [Wf|Wb][:,g] + bias[g]   via MFMA f16.
// (unchanged from round 2: ~44 us, near the 123 MB write roofline)
// ---------------------------------------------------------------------------
__global__ __launch_bounds__(256, 4) void embw_mfma(
    const float* __restrict__ emb,
    const float* __restrict__ Wf, const float* __restrict__ Wb,
    const float* __restrict__ bf, const float* __restrict__ bb,
    float* __restrict__ EW)
{
  __shared__ _Float16 As[64*EMBED];   // 32 KB
  const int tid = threadIdx.x;
  const int l   = tid & 63;
  const int w   = tid >> 6;
  const int r0  = blockIdx.x * 64;
  const int c0  = blockIdx.y * 64;
  const int nr  = min(64, VOCAB - r0);

  const float4* asrc = (const float4*)(emb + (size_t)r0*EMBED);
  for (int i = tid; i < nr*(EMBED/4); i += 256){
    float4 v = asrc[i];
    const int row = i >> 6;
    const int kc  = (i & 63) * 4;
    const int ks  = kc ^ ((row & 7) << 3);
    _Float16* dst = &As[row*EMBED + ks];
    dst[0]=(_Float16)v.x; dst[1]=(_Float16)v.y;
    dst[2]=(_Float16)v.z; dst[3]=(_Float16)v.w;
  }
  __syncthreads();

  const int cl = w*16 + (l & 15);
  const int cg = c0 + cl;
  const float* Wsrc = (cg < G4) ? (Wf + cg) : (Wb + (cg - G4));
  const int kg = (l >> 4) * 8;

  f32x4 acc[4] = {{0,0,0,0},{0,0,0,0},{0,0,0,0},{0,0,0,0}};

  for (int kk = 0; kk < EMBED/32; ++kk){
    const int kb = kk*32 + kg;
    f16x8 bfrag;
    #pragma unroll
    for (int j = 0; j < 8; ++j)
      bfrag[j] = (_Float16)Wsrc[(size_t)(kb + j)*G4];
    #pragma unroll
    for (int m = 0; m < 4; ++m){
      const int row = m*16 + (l & 15);
      const int ks  = kb ^ ((row & 7) << 3);
      f16x8 afrag = *(const f16x8*)&As[row*EMBED + ks];
      acc[m] = __builtin_amdgcn_mfma_f32_16x16x32_f16(afrag, bfrag, acc[m], 0, 0, 0);
    }
  }

  const float bv = (cg < G4) ? bf[cg] : bb[cg - G4];
  #pragma unroll
  for (int m = 0; m < 4; ++m){
    #pragma unroll
    for (int r = 0; r < 4; ++r){
      const int vrow = r0 + m*16 + (l >> 4)*4 + r;
      if (vrow < VOCAB)
        EW[(size_t)vrow*GW + cg] = acc[m][r] + bv;
    }
  }
}

// ---------------------------------------------------------------------------
// Kernel 2: recurrence via MFMA. One block = 4 batches x 1 direction.
// 512 threads = 8 waves; wave w owns gate-columns [w*64, w*64+64).
// U B-fragments resident in 64 VGPRs; h in swizzled LDS ([16][128] f16,
// rows 4..15 zero); xw prefetched 1 step ahead as the MFMA C-in.
// Raw s_barrier + lgkmcnt(0) only -> xw vmcnt stays in flight.
// ---------------------------------------------------------------------------
__global__ __launch_bounds__(512, 2) void lstm_mfma(
    const int*   __restrict__ tokens,
    const float* __restrict__ EW,
    const float* __restrict__ Ufw, const float* __restrict__ Ubw,
    float* __restrict__ out)
{
  __shared__ float    z_lds[BPB][G4];     // 8 KB
  __shared__ _Float16 h_lds[16*HID];      // 4 KB, XOR-swizzled 32B chunks
  __shared__ int      tok_lds[BPB][TT];   // 8 KB

  const int tid = threadIdx.x;
  const int l   = tid & 63;
  const int w   = tid >> 6;              // wave 0..7
  const int dir = blockIdx.x & 1;
  const int b0  = (blockIdx.x >> 1) * BPB;

  for (int i = tid; i < 16*HID; i += 512) h_lds[i] = (_Float16)0.f;
  for (int i = tid; i < BPB*TT; i += 512)
    tok_lds[i >> 9][i & 511] = tokens[(b0 + (i >> 9))*TT + (i & 511)];
  __syncthreads();

  // ---- resident U B-fragments: ub[ktile][ntile], 64 VGPRs ----
  const float* U = dir ? Ubw : Ufw;
  f16x8 ub[4][4];
  {
    const int kg = (l >> 4) * 8;
    #pragma unroll
    for (int kt = 0; kt < 4; ++kt){
      #pragma unroll
      for (int nt = 0; nt < 4; ++nt){
        const int col = w*64 + nt*16 + (l & 15);
        f16x8 f;
        #pragma unroll
        for (int j = 0; j < 8; ++j)
          f[j] = (_Float16)U[(size_t)(kt*32 + kg + j)*G4 + col];
        ub[kt][nt] = f;
      }
    }
  }

  // gate-phase identity for this thread
  const int gb = tid >> 7;               // batch 0..3
  const int gj = tid & 127;              // hidden index
  float creg = 0.f, h_fin = 0.f;
  float* outp = out + (size_t)(b0+gb)*TT*(2*HID) + (size_t)dir*HID + gj;

  // ---- xw prefetch for step 0 ----
  f32x4 xwv[4], xwn[4];
  #pragma unroll
  for (int nt = 0; nt < 4; ++nt) xwv[nt] = (f32x4){0,0,0,0};
  if (l < 16){
    const int tcur = dir ? (TT-1) : 0;
    #pragma unroll
    for (int r = 0; r < 4; ++r){
      const int tk = tok_lds[r][tcur];
      const float* src = EW + (size_t)tk*GW + dir*G4 + w*64 + l;
      #pragma unroll
      for (int nt = 0; nt < 4; ++nt) xwv[nt][r] = src[nt*16];
    }
  }
  __syncthreads();

  for (int s = 0; s < TT; ++s){
    const int t = dir ? (TT-1-s) : s;

    // ---- prefetch xw for step s+1 (vm stays in flight across barriers) ----
    {
      int tn = dir ? (TT-2-s) : (s+1);
      tn = min(max(tn, 0), TT-1);
      if (l < 16){
        #pragma unroll
        for (int r = 0; r < 4; ++r){
          const int tk = tok_lds[r][tn];
          const float* src = EW + (size_t)tk*GW + dir*G4 + w*64 + l;
          #pragma unroll
          for (int nt = 0; nt < 4; ++nt) xwn[nt][r] = src[nt*16];
        }
      }
    }

    // ---- MFMA: z = xw + h @ U ----
    f32x4 acc0 = xwv[0], acc1 = xwv[1], acc2 = xwv[2], acc3 = xwv[3];
    #pragma unroll
    for (int kt = 0; kt < 4; ++kt){
      const int row   = l & 15;
      const int hi    = l >> 4;
      const int chunk = kt*2 + (hi >> 1);
      const int addr  = row*256 + ((chunk ^ (row & 7)) << 5) + (hi & 1)*16;
      const f16x8 af  = *(const f16x8*)((const char*)h_lds + addr);
      acc0 = __builtin_amdgcn_mfma_f32_16x16x32_f16(af, ub[kt][0], acc0, 0, 0, 0);
      acc1 = __builtin_amdgcn_mfma_f32_16x16x32_f16(af, ub[kt][1], acc1, 0, 0, 0);
      acc2 = __builtin_amdgcn_mfma_f32_16x16x32_f16(af, ub[kt][2], acc2, 0, 0, 0);
      acc3 = __builtin_amdgcn_mfma_f32_16x16x32_f16(af, ub[kt][3], acc3, 0, 0, 0);
    }

    // ---- z -> LDS (only lanes holding real batch rows) ----
    if (l < 16){
      #pragma unroll
      for (int r = 0; r < 4; ++r){
        z_lds[r][w*64 +  0 + l] = acc0[r];
        z_lds[r][w*64 + 16 + l] = acc1[r];
        z_lds[r][w*64 + 32 + l] = acc2[r];
        z_lds[r][w*64 + 48 + l] = acc3[r];
      }
    }
    asm volatile("s_waitcnt lgkmcnt(0)" ::: "memory");
    __builtin_amdgcn_s_barrier();

    // ---- gate phase: 1 h-unit per thread ----
    {
      const float zi = z_lds[gb][gj];
      const float zf = z_lds[gb][gj + 128];
      const float zg = z_lds[gb][gj + 256];
      const float zo = z_lds[gb][gj + 384];
      const float cn = sigm(zf)*creg + sigm(zi)*fast_tanh(zg);
      creg = cn;
      const float hh = sigm(zo)*fast_tanh(cn);
      h_fin = hh;
      // swizzled f16 h write: row=gb, half index gj
      const int haddr = gb*256 + ((((gj >> 4) ^ gb) & 7) << 5) + (gj & 15)*2;
      *(_Float16*)((char*)h_lds + haddr) = (_Float16)hh;
      outp[(size_t)t*(2*HID)] = hh;     // global store: vm, never drained
    }
    asm volatile("s_waitcnt lgkmcnt(0)" ::: "memory");
    __builtin_amdgcn_s_barrier();

    #pragma unroll
    for (int nt = 0; nt < 4; ++nt) xwv[nt] = xwn[nt];
  }

  // ---- final h_T / c_T ----
  {
    const size_t O1  = (size_t)BB*TT*(2*HID);
    const size_t idx = (size_t)(b0+gb)*HID + gj;
    if (dir == 0){
      out[O1                        + idx] = h_fin;
      out[O1 +   (size_t)BB*HID     + idx] = creg;
    } else {
      out[O1 + 2*(size_t)BB*HID     + idx] = h_fin;
      out[O1 + 3*(size_t)BB*HID     + idx] = creg;
    }
  }
}

extern "C" void kernel_launch(void* const* d_in, const int* in_sizes, int n_in,
                              void* d_out, int out_size, void* d_ws, size_t ws_size,
                              hipStream_t stream)
{
  const int*   tokens = (const int*)  d_in[0];
  const float* emb    = (const float*)d_in[1];
  const float* Wf     = (const float*)d_in[2];
  const float* Ufw    = (const float*)d_in[3];
  const float* bf     = (const float*)d_in[4];
  const float* Wb     = (const float*)d_in[5];
  const float* Ubw    = (const float*)d_in[6];
  const float* bb     = (const float*)d_in[7];
  float* out = (float*)d_out;
  float* EW  = (float*)d_ws;          // 30000 x 1024 f32 = 122.88 MB

  embw_mfma<<<dim3((VOCAB + 63)/64, GW/64), 256, 0, stream>>>(emb, Wf, Wb, bf, bb, EW);
  lstm_mfma<<<(BB/BPB)*2, 512, 0, stream>>>(tokens, EW, Ufw, Ubw, out);
}

// Round 4
// 528.469 us; speedup vs baseline: 3.6017x; 1.3565x over previous
//
#include <hip/hip_runtime.h>
#include <hip/hip_bf16.h>
#include <stdint.h>

#define VOCAB 30000
#define EMBED 256
#define HID   128
#define BB    256
#define TT    512
#define G4    (4*HID)    // 512 gate columns per direction
#define GW    (2*G4)     // 1024 columns in embW (fw | bw)
#define BPB   2          // batches per lstm block

typedef _Float16 f16x8 __attribute__((ext_vector_type(8)));
typedef float    f32x4 __attribute__((ext_vector_type(4)));

__device__ __forceinline__ float sigm(float x){
  return 1.0f / (1.0f + __expf(-x));
}
__device__ __forceinline__ float fast_tanh(float x){
  float e = __expf(2.0f * x);
  return 1.0f - 2.0f / (e + 1.0f);
}

// ---------------------------------------------------------------------------
// Kernel 1: EW[v][g] = emb[v][:] @ [Wf|Wb][:,g] + bias[g]   via MFMA f16.
// ---------------------------------------------------------------------------
__global__ __launch_bounds__(256, 4) void embw_mfma(
    const float* __restrict__ emb,
    const float* __restrict__ Wf, const float* __restrict__ Wb,
    const float* __restrict__ bf, const float* __restrict__ bb,
    float* __restrict__ EW)
{
  __shared__ _Float16 As[64*EMBED];   // 32 KB
  const int tid = threadIdx.x;
  const int l   = tid & 63;
  const int w   = tid >> 6;
  const int r0  = blockIdx.x * 64;
  const int c0  = blockIdx.y * 64;
  const int nr  = min(64, VOCAB - r0);

  const float4* asrc = (const float4*)(emb + (size_t)r0*EMBED);
  for (int i = tid; i < nr*(EMBED/4); i += 256){
    float4 v = asrc[i];
    const int row = i >> 6;
    const int kc  = (i & 63) * 4;
    const int ks  = kc ^ ((row & 7) << 3);
    _Float16* dst = &As[row*EMBED + ks];
    dst[0]=(_Float16)v.x; dst[1]=(_Float16)v.y;
    dst[2]=(_Float16)v.z; dst[3]=(_Float16)v.w;
  }
  __syncthreads();

  const int cl = w*16 + (l & 15);
  const int cg = c0 + cl;
  const float* Wsrc = (cg < G4) ? (Wf + cg) : (Wb + (cg - G4));
  const int kg = (l >> 4) * 8;

  f32x4 acc[4] = {{0,0,0,0},{0,0,0,0},{0,0,0,0},{0,0,0,0}};

  for (int kk = 0; kk < EMBED/32; ++kk){
    const int kb = kk*32 + kg;
    f16x8 bfrag;
    #pragma unroll
    for (int j = 0; j < 8; ++j)
      bfrag[j] = (_Float16)Wsrc[(size_t)(kb + j)*G4];
    #pragma unroll
    for (int m = 0; m < 4; ++m){
      const int row = m*16 + (l & 15);
      const int ks  = kb ^ ((row & 7) << 3);
      f16x8 afrag = *(const f16x8*)&As[row*EMBED + ks];
      acc[m] = __builtin_amdgcn_mfma_f32_16x16x32_f16(afrag, bfrag, acc[m], 0, 0, 0);
    }
  }

  const float bv = (cg < G4) ? bf[cg] : bb[cg - G4];
  #pragma unroll
  for (int m = 0; m < 4; ++m){
    #pragma unroll
    for (int r = 0; r < 4; ++r){
      const int vrow = r0 + m*16 + (l >> 4)*4 + r;
      if (vrow < VOCAB)
        EW[(size_t)vrow*GW + cg] = acc[m][r] + bv;
    }
  }
}

// ---------------------------------------------------------------------------
// Kernel 2: recurrence. One block = 2 batches x 1 direction (256 blocks).
// 8 waves; wave w owns hidden units [w*16, w*16+16) with ALL 4 gates
// (n-tiles w, w+8, w+16, w+24 in units of 16 -> cols j, j+128, j+256, j+384).
// z never leaves the wave: bpermute redistributes C-layout -> 1 (batch,hid)
// per lane; gates in-register; only h (2x128 f16) crosses waves via a
// double-buffered swizzled LDS tile. ONE barrier per step.
// ---------------------------------------------------------------------------
__global__ __launch_bounds__(512, 2) void lstm_wave(
    const int*   __restrict__ tokens,
    const float* __restrict__ EW,
    const float* __restrict__ Ufw, const float* __restrict__ Ubw,
    float* __restrict__ out)
{
  __shared__ _Float16 h_lds[2][16*HID];   // 2 x 4 KB, XOR-swizzled 16B chunks
  __shared__ int      tok_lds[BPB*TT];    // 4 KB

  const int tid = threadIdx.x;
  const int l   = tid & 63;
  const int w   = tid >> 6;               // wave 0..7
  const int lr  = l & 15;
  const int hi  = l >> 4;
  const int dir = blockIdx.x & 1;
  const int b0  = (blockIdx.x >> 1) * BPB;

  for (int i = tid; i < 2*16*HID; i += 512) ((_Float16*)h_lds)[i] = (_Float16)0.f;
  for (int i = tid; i < BPB*TT; i += 512)
    tok_lds[i] = tokens[(b0 + (i >> 9))*TT + (i & 511)];
  __syncthreads();

  // ---- resident U B-fragments: ub[kt][gate], 64 VGPRs ----
  const float* U = dir ? Ubw : Ufw;
  f16x8 ub[4][4];
  #pragma unroll
  for (int kt = 0; kt < 4; ++kt){
    #pragma unroll
    for (int g = 0; g < 4; ++g){
      const int col = g*128 + w*16 + lr;
      f16x8 f;
      #pragma unroll
      for (int j = 0; j < 8; ++j)
        f[j] = (_Float16)U[(size_t)(kt*32 + hi*8 + j)*G4 + col];
      ub[kt][g] = f;
    }
  }

  const int  rb   = hi & 1;               // this lane's batch (lanes <32 valid)
  const int  gcol = w*16 + lr;            // this lane's hidden unit
  float creg = 0.f, hreg = 0.f;

  // ---- xw prefetch for step 0 (lanes replicate lane lr's 64B line) ----
  float xwc[4][2], xwn[4][2];
  {
    const int t0  = dir ? (TT-1) : 0;
    const int tk0 = tok_lds[t0];
    const int tk1 = tok_lds[TT + t0];
    const float* e0 = EW + (size_t)tk0*GW + dir*G4 + gcol;
    const float* e1 = EW + (size_t)tk1*GW + dir*G4 + gcol;
    #pragma unroll
    for (int g = 0; g < 4; ++g){ xwc[g][0] = e0[g*128]; xwc[g][1] = e1[g*128]; }
  }

  for (int s = 0; s < TT; ++s){
    const int t   = dir ? (TT-1-s) : s;
    const int cur = s & 1, nxt = cur ^ 1;

    // ---- A-fragments: h rows=batches, swizzled, 2-way-conflict-free ----
    f16x8 ha[4];
    #pragma unroll
    for (int kt = 0; kt < 4; ++kt){
      const int chunk = (kt*4 + hi) ^ (lr & 7);
      ha[kt] = *(const f16x8*)((const char*)h_lds[cur] + lr*256 + chunk*16);
    }

    // ---- xw prefetch s+1 (vm stays in flight across the barrier) ----
    {
      int tn = dir ? (TT-2-s) : (s+1);
      tn = tn < 0 ? 0 : (tn > TT-1 ? TT-1 : tn);
      const int tk0 = tok_lds[tn];
      const int tk1 = tok_lds[TT + tn];
      const float* e0 = EW + (size_t)tk0*GW + dir*G4 + gcol;
      const float* e1 = EW + (size_t)tk1*GW + dir*G4 + gcol;
      #pragma unroll
      for (int g = 0; g < 4; ++g){ xwn[g][0] = e0[g*128]; xwn[g][1] = e1[g*128]; }
    }

    // ---- MFMA: z = xw + h @ U, 4 independent gate chains ----
    f32x4 acc[4];
    #pragma unroll
    for (int g = 0; g < 4; ++g) acc[g] = (f32x4){xwc[g][0], xwc[g][1], 0.f, 0.f};
    #pragma unroll
    for (int kt = 0; kt < 4; ++kt){
      #pragma unroll
      for (int g = 0; g < 4; ++g)
        acc[g] = __builtin_amdgcn_mfma_f32_16x16x32_f16(ha[kt], ub[kt][g], acc[g], 0, 0, 0);
    }

    // ---- redistribute z: lane l pulls batch rb=hi&1, col gcol from lane lr ----
    float z[4];
    #pragma unroll
    for (int g = 0; g < 4; ++g){
      const int p0 = __builtin_amdgcn_ds_bpermute(lr << 2, __float_as_int(acc[g][0]));
      const int p1 = __builtin_amdgcn_ds_bpermute(lr << 2, __float_as_int(acc[g][1]));
      z[g] = __int_as_float(rb ? p1 : p0);
    }

    // ---- gates (i,f,g,o), one (batch,hid) per lane ----
    const float cn = sigm(z[1])*creg + sigm(z[0])*fast_tanh(z[2]);
    creg = cn;
    const float hh = sigm(z[3])*fast_tanh(cn);
    hreg = hh;

    if (l < 32){
      const int chunk = (gcol >> 3) ^ (rb & 7);
      *(_Float16*)((char*)h_lds[nxt] + rb*256 + chunk*16 + (gcol & 7)*2) = (_Float16)hh;
      out[((size_t)(b0+rb)*TT + t)*(2*HID) + (size_t)dir*HID + gcol] = hh;
    }

    asm volatile("s_waitcnt lgkmcnt(0)" ::: "memory");
    __builtin_amdgcn_s_barrier();

    #pragma unroll
    for (int g = 0; g < 4; ++g){ xwc[g][0] = xwn[g][0]; xwc[g][1] = xwn[g][1]; }
  }

  // ---- final h_T / c_T ----
  if (l < 32){
    const size_t O1  = (size_t)BB*TT*(2*HID);
    const size_t idx = (size_t)(b0+rb)*HID + gcol;
    if (dir == 0){
      out[O1                    + idx] = hreg;
      out[O1 +   (size_t)BB*HID + idx] = creg;
    } else {
      out[O1 + 2*(size_t)BB*HID + idx] = hreg;
      out[O1 + 3*(size_t)BB*HID + idx] = creg;
    }
  }
}

extern "C" void kernel_launch(void* const* d_in, const int* in_sizes, int n_in,
                              void* d_out, int out_size, void* d_ws, size_t ws_size,
                              hipStream_t stream)
{
  const int*   tokens = (const int*)  d_in[0];
  const float* emb    = (const float*)d_in[1];
  const float* Wf     = (const float*)d_in[2];
  const float* Ufw    = (const float*)d_in[3];
  const float* bf     = (const float*)d_in[4];
  const float* Wb     = (const float*)d_in[5];
  const float* Ubw    = (const float*)d_in[6];
  const float* bb     = (const float*)d_in[7];
  float* out = (float*)d_out;
  float* EW  = (float*)d_ws;          // 30000 x 1024 f32 = 122.88 MB

  embw_mfma<<<dim3((VOCAB + 63)/64, GW/64), 256, 0, stream>>>(emb, Wf, Wb, bf, bb, EW);
  lstm_wave<<<(BB/BPB)*2, 512, 0, stream>>>(tokens, EW, Ufw, Ubw, out);
}